// Round 1
// baseline (165.772 us; speedup 1.0000x reference)
//
#include <hip/hip_runtime.h>

#define NN 1024
#define JSPLIT 8
#define JRANGE (NN / JSPLIT)   // 128
#define JCHUNK 16
#define RPT 16
#define LDS_Q 336              // padded float4 count per d-plane
#define LDS_FPD (LDS_Q * 4)    // floats per d-plane (1344)

__device__ __forceinline__ float celu1(float v) {
    return v > 0.0f ? v : expm1f(v);
}

// c[b,r] = sum_j sum_d x[b,j,d] * x[b,(j+r)%N,d]   (1/N applied in mlp_kernel)
// grid: 128*JSPLIT blocks of 64 threads; block = (b, j-slice); thread: 16 consecutive r
__global__ __launch_bounds__(64) void autocorr_kernel(const float* __restrict__ x,
                                                      float* __restrict__ cacc) {
    __shared__ float4 lds4[3][LDS_Q];
    const int b = blockIdx.x >> 3;
    const int jstart = (blockIdx.x & 7) * JRANGE;
    const int tid = threadIdx.x;

    // Stage x[b] (1024x3) -> LDS transposed [d][j], padded (+4 floats per 16),
    // first 32 j duplicated at j+1024 for mod-free sliding windows.
    {
        const float4* xb4 = (const float4*)(x + (size_t)b * NN * 3);
        float* lf = (float*)lds4;
        for (int i = tid; i < 768; i += 64) {
            float4 v = xb4[i];
            int g = i * 4;
            float vv[4] = {v.x, v.y, v.z, v.w};
            #pragma unroll
            for (int u = 0; u < 4; ++u) {
                int gg = g + u;
                int j = gg / 3;
                int d = gg - 3 * j;
                int pj = j + ((j >> 4) << 2);
                lf[d * LDS_FPD + pj] = vv[u];
            }
        }
        if (tid < 24) {   // duplicate j in [0,32)
            float4 v = xb4[tid];
            int g = tid * 4;
            float vv[4] = {v.x, v.y, v.z, v.w};
            #pragma unroll
            for (int u = 0; u < 4; ++u) {
                int gg = g + u;
                int j = gg / 3 + 1024;
                int d = gg - 3 * (gg / 3);
                int pj = j + ((j >> 4) << 2);
                lf[d * LDS_FPD + pj] = vv[u];
            }
        }
    }
    __syncthreads();

    const int rb = tid * RPT;
    float acc[RPT];
    #pragma unroll
    for (int r = 0; r < RPT; ++r) acc[r] = 0.0f;

    #pragma unroll 1
    for (int jc = 0; jc < JRANGE / JCHUNK; ++jc) {
        const int j0 = jstart + jc * JCHUNK;
        #pragma unroll 1
        for (int d = 0; d < 3; ++d) {
            const float4* L = lds4[d];
            // uniform factor x[j0..j0+15] (broadcast reads)
            const int qu = j0 >> 2;            // multiple of 4
            const int pu = qu + (qu >> 2);
            float uv[JCHUNK];
            *(float4*)&uv[0]  = L[pu + 0];
            *(float4*)&uv[4]  = L[pu + 1];
            *(float4*)&uv[8]  = L[pu + 2];
            *(float4*)&uv[12] = L[pu + 3];
            // sliding window x[(j0+rb) .. +30]
            const int kw = (j0 + rb) & (NN - 1);   // multiple of 16
            const int qw = kw >> 2;
            const int pw = qw + (qw >> 2);
            float wv[2 * JCHUNK];
            *(float4*)&wv[0]  = L[pw + 0];
            *(float4*)&wv[4]  = L[pw + 1];
            *(float4*)&wv[8]  = L[pw + 2];
            *(float4*)&wv[12] = L[pw + 3];
            *(float4*)&wv[16] = L[pw + 5];   // +1 pad gap after 4 logical float4s
            *(float4*)&wv[20] = L[pw + 6];
            *(float4*)&wv[24] = L[pw + 7];
            *(float4*)&wv[28] = L[pw + 8];
            #pragma unroll
            for (int jj = 0; jj < JCHUNK; ++jj) {
                const float uj = uv[jj];
                #pragma unroll
                for (int rr = 0; rr < RPT; ++rr)
                    acc[rr] = fmaf(uj, wv[jj + rr], acc[rr]);
            }
        }
    }

    float* cb = cacc + (size_t)b * NN + rb;
    #pragma unroll
    for (int rr = 0; rr < RPT; ++rr)
        atomicAdd(&cb[rr], acc[rr]);
}

// Fused MLP: y[b] = celu(celu(c/N @ W1 + b1) @ W2 + b2) @ W3 + b3
// grid: 128 blocks of 256 threads (one block per batch row)
__global__ __launch_bounds__(256) void mlp_kernel(const float* __restrict__ cacc,
                                                  const float* __restrict__ W1,
                                                  const float* __restrict__ b1,
                                                  const float* __restrict__ W2,
                                                  const float* __restrict__ b2,
                                                  const float* __restrict__ W3,
                                                  const float* __restrict__ b3,
                                                  float* __restrict__ out) {
    __shared__ float cl[NN];
    __shared__ float4 hp4[8][32];
    __shared__ float h[128];
    __shared__ float red[128];
    const int b = blockIdx.x;
    const int tid = threadIdx.x;

    {
        float4 v = ((const float4*)(cacc + (size_t)b * NN))[tid];
        const float sc = 1.0f / (float)NN;
        cl[tid * 4 + 0] = v.x * sc;
        cl[tid * 4 + 1] = v.y * sc;
        cl[tid * 4 + 2] = v.z * sc;
        cl[tid * 4 + 3] = v.w * sc;
    }
    __syncthreads();

    const int tq = tid & 31;     // 4 output cols per thread
    const int ks = tid >> 5;     // 8-way split-K
    const float4* W1v = (const float4*)W1;
    float4 s = make_float4(0.f, 0.f, 0.f, 0.f);
    #pragma unroll 8
    for (int k = ks * 128; k < ks * 128 + 128; ++k) {
        const float cv = cl[k];
        const float4 wv = W1v[k * 32 + tq];
        s.x = fmaf(cv, wv.x, s.x);
        s.y = fmaf(cv, wv.y, s.y);
        s.z = fmaf(cv, wv.z, s.z);
        s.w = fmaf(cv, wv.w, s.w);
    }
    hp4[ks][tq] = s;
    __syncthreads();
    if (tid < 32) {
        float4 a = hp4[0][tid];
        #pragma unroll
        for (int j = 1; j < 8; ++j) {
            float4 t = hp4[j][tid];
            a.x += t.x; a.y += t.y; a.z += t.z; a.w += t.w;
        }
        const float4 bb = ((const float4*)b1)[tid];
        h[tid * 4 + 0] = celu1(a.x + bb.x);
        h[tid * 4 + 1] = celu1(a.y + bb.y);
        h[tid * 4 + 2] = celu1(a.z + bb.z);
        h[tid * 4 + 3] = celu1(a.w + bb.w);
    }
    __syncthreads();

    const float4* W2v = (const float4*)W2;
    float4 s2 = make_float4(0.f, 0.f, 0.f, 0.f);
    #pragma unroll
    for (int k = ks * 16; k < ks * 16 + 16; ++k) {
        const float hv = h[k];
        const float4 wv = W2v[k * 32 + tq];
        s2.x = fmaf(hv, wv.x, s2.x);
        s2.y = fmaf(hv, wv.y, s2.y);
        s2.z = fmaf(hv, wv.z, s2.z);
        s2.w = fmaf(hv, wv.w, s2.w);
    }
    hp4[ks][tq] = s2;
    __syncthreads();
    if (tid < 32) {
        float4 a = hp4[0][tid];
        #pragma unroll
        for (int j = 1; j < 8; ++j) {
            float4 t = hp4[j][tid];
            a.x += t.x; a.y += t.y; a.z += t.z; a.w += t.w;
        }
        const float4 bb = ((const float4*)b2)[tid];
        h[tid * 4 + 0] = celu1(a.x + bb.x);
        h[tid * 4 + 1] = celu1(a.y + bb.y);
        h[tid * 4 + 2] = celu1(a.z + bb.z);
        h[tid * 4 + 3] = celu1(a.w + bb.w);
    }
    __syncthreads();

    if (tid < 128) red[tid] = h[tid] * W3[tid];
    __syncthreads();
    for (int st = 64; st > 0; st >>= 1) {
        if (tid < st) red[tid] += red[tid + st];
        __syncthreads();
    }
    if (tid == 0) out[b] = red[0] + b3[0];
}

extern "C" void kernel_launch(void* const* d_in, const int* in_sizes, int n_in,
                              void* d_out, int out_size, void* d_ws, size_t ws_size,
                              hipStream_t stream) {
    const float* x  = (const float*)d_in[0];
    const float* W1 = (const float*)d_in[1];
    const float* b1 = (const float*)d_in[2];
    const float* W2 = (const float*)d_in[3];
    const float* b2 = (const float*)d_in[4];
    const float* W3 = (const float*)d_in[5];
    const float* b3 = (const float*)d_in[6];
    float* out = (float*)d_out;

    float* cacc = (float*)d_ws;  // 128*1024 f32 = 512 KB accumulator
    hipMemsetAsync(cacc, 0, (size_t)128 * NN * sizeof(float), stream);
    autocorr_kernel<<<128 * JSPLIT, 64, 0, stream>>>(x, cacc);
    mlp_kernel<<<128, 256, 0, stream>>>(cacc, W1, b1, W2, b2, W3, b3, out);
}

// Round 2
// 86.363 us; speedup vs baseline: 1.9195x; 1.9195x over previous
//
#include <hip/hip_runtime.h>

#define NN 1024
#define RPT 16          // r per thread, consecutive
#define JCHUNK 16       // j per (thread, iteration)
#define LDS_Q 336       // padded float4 per d-plane
#define LDS_FPD (LDS_Q * 4)

__device__ __forceinline__ float celu1(float v) {
    return v > 0.0f ? v : expm1f(v);
}

// Partial circular autocorrelation, exploiting c[r] == c[N-r]:
// pout[bid][r'] = sum over this block's 128 j of sum_d x[b,j,d]*x[b,(j+r')%N,d],
// r' in [0,512). grid = 128 b x 8 jslices, block = 256 thr = 32 r-thr x 8 jsub.
__global__ __launch_bounds__(256, 4) void autocorr_kernel(const float* __restrict__ x,
                                                          float* __restrict__ pout) {
    __shared__ float4 lds4[3][LDS_Q];
    __shared__ float red[8][32][17];
    const int b   = blockIdx.x >> 3;
    const int js  = blockIdx.x & 7;
    const int tid = threadIdx.x;

    // Stage x[b] (1024x3) -> LDS transposed [d][j], +4-float pad per 16 j,
    // j in [0,32) duplicated at j+1024 for mod-free windows.
    {
        const float4* xb4 = (const float4*)(x + (size_t)b * NN * 3);
        float* lf = (float*)lds4;
        for (int i = tid; i < 768; i += 256) {
            float4 v = xb4[i];
            int g = i * 4;
            float vv[4] = {v.x, v.y, v.z, v.w};
            #pragma unroll
            for (int u = 0; u < 4; ++u) {
                int gg = g + u;
                int j = gg / 3;
                int d = gg - 3 * j;
                int pj = j + ((j >> 4) << 2);
                lf[d * LDS_FPD + pj] = vv[u];
            }
        }
        if (tid < 24) {
            float4 v = xb4[tid];
            int g = tid * 4;
            float vv[4] = {v.x, v.y, v.z, v.w};
            #pragma unroll
            for (int u = 0; u < 4; ++u) {
                int gg = g + u;
                int j = gg / 3 + 1024;
                int d = gg - 3 * (gg / 3);
                int pj = j + ((j >> 4) << 2);
                lf[d * LDS_FPD + pj] = vv[u];
            }
        }
    }
    __syncthreads();

    const int rt   = tid & 31;        // r-thread: r block [rt*16, rt*16+16)
    const int part = tid >> 5;        // j-sub-slice 0..7
    const int rb   = rt * RPT;        // < 512
    const int j0   = js * 128 + part * JCHUNK;

    float acc[RPT];
    #pragma unroll
    for (int r = 0; r < RPT; ++r) acc[r] = 0.0f;

    #pragma unroll 1
    for (int d = 0; d < 3; ++d) {
        const float4* L = lds4[d];
        // uniform factor x[j0..j0+15] (half-wave broadcast)
        const int qu = j0 >> 2;
        const int pu = qu + (qu >> 2);
        float uv[JCHUNK];
        *(float4*)&uv[0]  = L[pu + 0];
        *(float4*)&uv[4]  = L[pu + 1];
        *(float4*)&uv[8]  = L[pu + 2];
        *(float4*)&uv[12] = L[pu + 3];
        // sliding window x[(j0+rb) .. +31]
        const int kw = (j0 + rb) & (NN - 1);   // multiple of 16
        const int qw = kw >> 2;
        const int pw = qw + (qw >> 2);
        float wv[2 * JCHUNK];
        *(float4*)&wv[0]  = L[pw + 0];
        *(float4*)&wv[4]  = L[pw + 1];
        *(float4*)&wv[8]  = L[pw + 2];
        *(float4*)&wv[12] = L[pw + 3];
        *(float4*)&wv[16] = L[pw + 5];   // pad quad skipped
        *(float4*)&wv[20] = L[pw + 6];
        *(float4*)&wv[24] = L[pw + 7];
        *(float4*)&wv[28] = L[pw + 8];
        #pragma unroll
        for (int jj = 0; jj < JCHUNK; ++jj) {
            const float uj = uv[jj];
            #pragma unroll
            for (int rr = 0; rr < RPT; ++rr)
                acc[rr] = fmaf(uj, wv[jj + rr], acc[rr]);
        }
    }

    // in-block reduction over the 8 j-sub-slices
    #pragma unroll
    for (int rr = 0; rr < RPT; ++rr) red[part][rt][rr] = acc[rr];
    __syncthreads();

    const int r2  = tid * 2;          // 0..510, covers 512 outputs
    const int rt2 = r2 >> 4;
    const int rr2 = r2 & 15;
    float s0 = 0.0f, s1 = 0.0f;
    #pragma unroll
    for (int p = 0; p < 8; ++p) {
        s0 += red[p][rt2][rr2];
        s1 += red[p][rt2][rr2 + 1];
    }
    ((float2*)(pout + (size_t)blockIdx.x * 512))[tid] = make_float2(s0, s1);
}

// Fused MLP: builds full c[1024] from 8 partials + symmetry + direct c[512],
// then y[b] = celu(celu(c/N @ W1 + b1) @ W2 + b2) @ W3 + b3
__global__ __launch_bounds__(256) void mlp_kernel(const float* __restrict__ x,
                                                  const float* __restrict__ pout,
                                                  const float* __restrict__ W1,
                                                  const float* __restrict__ b1,
                                                  const float* __restrict__ W2,
                                                  const float* __restrict__ b2,
                                                  const float* __restrict__ W3,
                                                  const float* __restrict__ b3,
                                                  float* __restrict__ out) {
    __shared__ float cl[NN];
    __shared__ float4 hp4[8][32];
    __shared__ float h[128];
    __shared__ float rtmp[256];
    const int b = blockIdx.x;
    const int tid = threadIdx.x;
    const float sc = 1.0f / (float)NN;

    // ---- c[512] = 2 * sum_{f<1536} xf[f]*xf[f+1536] ----
    {
        const float2* xb2 = (const float2*)(x + (size_t)b * 3072);
        float ps = 0.0f;
        #pragma unroll
        for (int i = 0; i < 3; ++i) {
            float2 a = xb2[tid * 3 + i];
            float2 c = xb2[tid * 3 + i + 768];
            ps = fmaf(a.x, c.x, ps);
            ps = fmaf(a.y, c.y, ps);
        }
        rtmp[tid] = ps;
    }
    __syncthreads();
    for (int st = 128; st > 0; st >>= 1) {
        if (tid < st) rtmp[tid] += rtmp[tid + st];
        __syncthreads();
    }

    // ---- cl[0..511] from partial sums, mirror to cl[513..1023] ----
    if (tid < 128) {
        const float4* pv = (const float4*)(pout + (size_t)b * 8 * 512);
        float4 a = pv[tid];
        #pragma unroll
        for (int s = 1; s < 8; ++s) {
            float4 t = pv[s * 128 + tid];
            a.x += t.x; a.y += t.y; a.z += t.z; a.w += t.w;
        }
        a.x *= sc; a.y *= sc; a.z *= sc; a.w *= sc;
        const int i0 = tid * 4;
        float av[4] = {a.x, a.y, a.z, a.w};
        #pragma unroll
        for (int u = 0; u < 4; ++u) {
            cl[i0 + u] = av[u];
            if (i0 + u > 0) cl[NN - (i0 + u)] = av[u];
        }
    }
    if (tid == 0) cl[512] = 2.0f * rtmp[0] * sc;
    __syncthreads();

    // ---- layer 1: h = celu(cl @ W1 + b1) ----
    const int tq = tid & 31;     // 4 output cols per thread
    const int ks = tid >> 5;     // 8-way split-K
    const float4* W1v = (const float4*)W1;
    float4 s = make_float4(0.f, 0.f, 0.f, 0.f);
    #pragma unroll 8
    for (int k = ks * 128; k < ks * 128 + 128; ++k) {
        const float cv = cl[k];
        const float4 wv = W1v[k * 32 + tq];
        s.x = fmaf(cv, wv.x, s.x);
        s.y = fmaf(cv, wv.y, s.y);
        s.z = fmaf(cv, wv.z, s.z);
        s.w = fmaf(cv, wv.w, s.w);
    }
    hp4[ks][tq] = s;
    __syncthreads();
    if (tid < 32) {
        float4 a = hp4[0][tid];
        #pragma unroll
        for (int j = 1; j < 8; ++j) {
            float4 t = hp4[j][tid];
            a.x += t.x; a.y += t.y; a.z += t.z; a.w += t.w;
        }
        const float4 bb = ((const float4*)b1)[tid];
        h[tid * 4 + 0] = celu1(a.x + bb.x);
        h[tid * 4 + 1] = celu1(a.y + bb.y);
        h[tid * 4 + 2] = celu1(a.z + bb.z);
        h[tid * 4 + 3] = celu1(a.w + bb.w);
    }
    __syncthreads();

    // ---- layer 2 ----
    const float4* W2v = (const float4*)W2;
    float4 s2 = make_float4(0.f, 0.f, 0.f, 0.f);
    #pragma unroll
    for (int k = ks * 16; k < ks * 16 + 16; ++k) {
        const float hv = h[k];
        const float4 wv = W2v[k * 32 + tq];
        s2.x = fmaf(hv, wv.x, s2.x);
        s2.y = fmaf(hv, wv.y, s2.y);
        s2.z = fmaf(hv, wv.z, s2.z);
        s2.w = fmaf(hv, wv.w, s2.w);
    }
    hp4[ks][tq] = s2;
    __syncthreads();
    if (tid < 32) {
        float4 a = hp4[0][tid];
        #pragma unroll
        for (int j = 1; j < 8; ++j) {
            float4 t = hp4[j][tid];
            a.x += t.x; a.y += t.y; a.z += t.z; a.w += t.w;
        }
        const float4 bb = ((const float4*)b2)[tid];
        h[tid * 4 + 0] = celu1(a.x + bb.x);
        h[tid * 4 + 1] = celu1(a.y + bb.y);
        h[tid * 4 + 2] = celu1(a.z + bb.z);
        h[tid * 4 + 3] = celu1(a.w + bb.w);
    }
    __syncthreads();

    // ---- layer 3 ----
    if (tid < 128) rtmp[tid] = h[tid] * W3[tid];
    __syncthreads();
    for (int st = 64; st > 0; st >>= 1) {
        if (tid < st && tid < 128) rtmp[tid] += rtmp[tid + st];
        __syncthreads();
    }
    if (tid == 0) out[b] = rtmp[0] + b3[0];
}

extern "C" void kernel_launch(void* const* d_in, const int* in_sizes, int n_in,
                              void* d_out, int out_size, void* d_ws, size_t ws_size,
                              hipStream_t stream) {
    const float* x  = (const float*)d_in[0];
    const float* W1 = (const float*)d_in[1];
    const float* b1 = (const float*)d_in[2];
    const float* W2 = (const float*)d_in[3];
    const float* b2 = (const float*)d_in[4];
    const float* W3 = (const float*)d_in[5];
    const float* b3 = (const float*)d_in[6];
    float* out = (float*)d_out;

    float* pout = (float*)d_ws;  // 1024 x 512 f32 = 2 MB partials
    autocorr_kernel<<<128 * 8, 256, 0, stream>>>(x, pout);
    mlp_kernel<<<128, 256, 0, stream>>>(x, pout, W1, b1, W2, b2, W3, b3, out);
}

// Round 3
// 83.774 us; speedup vs baseline: 1.9788x; 1.0309x over previous
//
#include <hip/hip_runtime.h>

#define NN 1024
#define RPT 16            // r per thread (consecutive)
#define JCHUNK 16         // j per chunk
#define NPART 16          // j-slices (threads: 32 rt x 16 part)
#define LDS_Q 336         // padded float4 per d-plane
#define LDS_FPD (LDS_Q * 4)

__device__ __forceinline__ float celu1(float v) {
    return v > 0.0f ? v : expm1f(v);
}

// One block per batch row: circular autocorr (r<512, symmetry c[r]=c[N-r]) + fused MLP.
__global__ __launch_bounds__(512, 2) void fused_kernel(const float* __restrict__ x,
                                                       const float* __restrict__ W1,
                                                       const float* __restrict__ b1,
                                                       const float* __restrict__ W2,
                                                       const float* __restrict__ b2,
                                                       const float* __restrict__ W3,
                                                       const float* __restrict__ b3,
                                                       float* __restrict__ out) {
    __shared__ union {
        float4 stage[3][LDS_Q];                 // 16128 B : padded x[b] transposed [d][j]
        float  red[NPART][32][20];              // 40960 B : partial reduction
        struct {                                 //  9728 B : MLP phase
            float4 hp4[16][32];
            float  h[128];
            float  rtmp[128];
        } m;
    } U;
    __shared__ float cl[NN];
    __shared__ float c512p[8];

    const int b   = blockIdx.x;
    const int tid = threadIdx.x;

    // ---- stage x[b] (1024x3 = 768 float4) -> LDS [d][j] with +4-float pad per 16 j;
    //      j in [0,48) duplicated at j+1024 for mod-free sliding windows ----
    {
        const float4* xb4 = (const float4*)(x + (size_t)b * NN * 3);
        float* lf = (float*)U.stage;
        for (int i = tid; i < 768; i += 512) {
            float4 v = xb4[i];
            int g = i * 4;
            float vv[4] = {v.x, v.y, v.z, v.w};
            #pragma unroll
            for (int u = 0; u < 4; ++u) {
                int gg = g + u;
                int j = gg / 3;
                int d = gg - 3 * j;
                int pj = j + ((j >> 4) << 2);
                lf[(size_t)d * LDS_FPD + pj] = vv[u];
            }
        }
        if (tid < 36) {   // duplicate j in [0,48): 144 floats = 36 float4
            float4 v = xb4[tid];
            int g = tid * 4;
            float vv[4] = {v.x, v.y, v.z, v.w};
            #pragma unroll
            for (int u = 0; u < 4; ++u) {
                int gg = g + u;
                int j = gg / 3 + 1024;
                int d = gg - 3 * (gg / 3);
                int pj = j + ((j >> 4) << 2);
                lf[(size_t)d * LDS_FPD + pj] = vv[u];
            }
        }
    }
    __syncthreads();

    // ---- autocorr compute: thread (rt, part): r in [rt*16, rt*16+16), j in part's 64 ----
    const int rt   = tid & 31;
    const int part = tid >> 5;
    const int rb   = rt * RPT;            // < 512

    float acc[RPT];
    #pragma unroll
    for (int r = 0; r < RPT; ++r) acc[r] = 0.0f;

    #pragma unroll 1
    for (int ch = 0; ch < 4; ++ch) {
        const int j0 = part * 64 + ch * JCHUNK;
        #pragma unroll 1
        for (int d = 0; d < 3; ++d) {
            const float4* L = (const float4*)((const float*)U.stage + (size_t)d * LDS_FPD);
            const int qu = j0 >> 2;          // multiple of 4
            const int pu = qu + (qu >> 2);
            float uv[JCHUNK];
            *(float4*)&uv[0]  = L[pu + 0];
            *(float4*)&uv[4]  = L[pu + 1];
            *(float4*)&uv[8]  = L[pu + 2];
            *(float4*)&uv[12] = L[pu + 3];
            const int kw = (j0 + rb) & (NN - 1);   // multiple of 16
            const int qw = kw >> 2;
            const int pw = qw + (qw >> 2);
            float wv[2 * JCHUNK];
            *(float4*)&wv[0]  = L[pw + 0];
            *(float4*)&wv[4]  = L[pw + 1];
            *(float4*)&wv[8]  = L[pw + 2];
            *(float4*)&wv[12] = L[pw + 3];
            *(float4*)&wv[16] = L[pw + 5];   // pad quad skipped
            *(float4*)&wv[20] = L[pw + 6];
            *(float4*)&wv[24] = L[pw + 7];
            *(float4*)&wv[28] = L[pw + 8];
            #pragma unroll
            for (int jj = 0; jj < JCHUNK; ++jj) {
                const float uj = uv[jj];
                #pragma unroll
                for (int rr = 0; rr < RPT; ++rr)
                    acc[rr] = fmaf(uj, wv[jj + rr], acc[rr]);
            }
        }
    }

    // ---- c[512] = 2 * sum_{j<512} x[j].x[j+512]  (reads stage; before red aliases it) ----
    {
        const float* lf = (const float*)U.stage;
        const int j  = tid;                       // 0..511
        const int pj = j + ((j >> 4) << 2);
        const int j2 = j + 512;
        const int p2 = j2 + ((j2 >> 4) << 2);
        float ps = 0.0f;
        #pragma unroll
        for (int d = 0; d < 3; ++d)
            ps = fmaf(lf[(size_t)d * LDS_FPD + pj], lf[(size_t)d * LDS_FPD + p2], ps);
        #pragma unroll
        for (int off = 32; off > 0; off >>= 1)
            ps += __shfl_down(ps, off);
        if ((tid & 63) == 0) c512p[tid >> 6] = ps;
    }
    __syncthreads();   // stage reads done; red may alias

    // ---- in-block reduction over the 16 j-slices ----
    #pragma unroll
    for (int q = 0; q < 4; ++q)
        *(float4*)&U.red[part][rt][q * 4] = *(float4*)&acc[q * 4];
    __syncthreads();

    {
        const int r  = tid;          // 0..511
        const int rt2 = r >> 4;
        const int rr2 = r & 15;
        float s = 0.0f;
        #pragma unroll
        for (int p = 0; p < NPART; ++p) s += U.red[p][rt2][rr2];
        s *= (1.0f / (float)NN);
        cl[r] = s;
        if (r > 0) cl[NN - r] = s;
        if (r == 0) {
            float t = 0.0f;
            #pragma unroll
            for (int wv8 = 0; wv8 < 8; ++wv8) t += c512p[wv8];
            cl[512] = 2.0f * t * (1.0f / (float)NN);
        }
    }
    __syncthreads();

    // ---- layer 1: h = celu(cl @ W1 + b1); 16-way split-K x (32 thr x 4 cols) ----
    const int tq = tid & 31;
    const int ks = tid >> 5;       // 0..15
    {
        const float4* W1v = (const float4*)W1;
        float4 s = make_float4(0.f, 0.f, 0.f, 0.f);
        #pragma unroll 8
        for (int k = ks * 64; k < ks * 64 + 64; ++k) {
            const float cv = cl[k];
            const float4 wv = W1v[k * 32 + tq];
            s.x = fmaf(cv, wv.x, s.x);
            s.y = fmaf(cv, wv.y, s.y);
            s.z = fmaf(cv, wv.z, s.z);
            s.w = fmaf(cv, wv.w, s.w);
        }
        U.m.hp4[ks][tq] = s;
    }
    __syncthreads();
    if (tid < 32) {
        float4 a = U.m.hp4[0][tid];
        #pragma unroll
        for (int j = 1; j < 16; ++j) {
            float4 t = U.m.hp4[j][tid];
            a.x += t.x; a.y += t.y; a.z += t.z; a.w += t.w;
        }
        const float4 bb = ((const float4*)b1)[tid];
        U.m.h[tid * 4 + 0] = celu1(a.x + bb.x);
        U.m.h[tid * 4 + 1] = celu1(a.y + bb.y);
        U.m.h[tid * 4 + 2] = celu1(a.z + bb.z);
        U.m.h[tid * 4 + 3] = celu1(a.w + bb.w);
    }
    __syncthreads();

    // ---- layer 2 ----
    {
        const float4* W2v = (const float4*)W2;
        float4 s = make_float4(0.f, 0.f, 0.f, 0.f);
        #pragma unroll
        for (int k = ks * 8; k < ks * 8 + 8; ++k) {
            const float hv = U.m.h[k];
            const float4 wv = W2v[k * 32 + tq];
            s.x = fmaf(hv, wv.x, s.x);
            s.y = fmaf(hv, wv.y, s.y);
            s.z = fmaf(hv, wv.z, s.z);
            s.w = fmaf(hv, wv.w, s.w);
        }
        __syncthreads();             // h reads done before hp4 overwrite? (hp4/h disjoint) — keep for safety
        U.m.hp4[ks][tq] = s;
    }
    __syncthreads();
    if (tid < 32) {
        float4 a = U.m.hp4[0][tid];
        #pragma unroll
        for (int j = 1; j < 16; ++j) {
            float4 t = U.m.hp4[j][tid];
            a.x += t.x; a.y += t.y; a.z += t.z; a.w += t.w;
        }
        const float4 bb = ((const float4*)b2)[tid];
        U.m.h[tid * 4 + 0] = celu1(a.x + bb.x);
        U.m.h[tid * 4 + 1] = celu1(a.y + bb.y);
        U.m.h[tid * 4 + 2] = celu1(a.z + bb.z);
        U.m.h[tid * 4 + 3] = celu1(a.w + bb.w);
    }
    __syncthreads();

    // ---- layer 3 ----
    if (tid < 128) U.m.rtmp[tid] = U.m.h[tid] * W3[tid];
    __syncthreads();
    for (int st = 64; st > 0; st >>= 1) {
        if (tid < st) U.m.rtmp[tid] += U.m.rtmp[tid + st];
        __syncthreads();
    }
    if (tid == 0) out[b] = U.m.rtmp[0] + b3[0];
}

extern "C" void kernel_launch(void* const* d_in, const int* in_sizes, int n_in,
                              void* d_out, int out_size, void* d_ws, size_t ws_size,
                              hipStream_t stream) {
    const float* x  = (const float*)d_in[0];
    const float* W1 = (const float*)d_in[1];
    const float* b1 = (const float*)d_in[2];
    const float* W2 = (const float*)d_in[3];
    const float* b2 = (const float*)d_in[4];
    const float* W3 = (const float*)d_in[5];
    const float* b3 = (const float*)d_in[6];
    float* out = (float*)d_out;

    fused_kernel<<<128, 512, 0, stream>>>(x, W1, b1, W2, b2, W3, b3, out);
}